// Round 15
// baseline (202.242 us; speedup 1.0000x reference)
//
#include <hip/hip_runtime.h>

#define S_LEN 4096
#define NH 12
#define HD 64
#define DMODEL 768
#define BATCH 2
#define MTOT (BATCH * S_LEN) /* 8192 */

typedef __bf16 bf16x8 __attribute__((ext_vector_type(8)));
typedef __bf16 bf16x4 __attribute__((ext_vector_type(4)));
typedef float f32x4 __attribute__((ext_vector_type(4)));
typedef float f32x8 __attribute__((ext_vector_type(8)));

#define SM_SCALE_LOG2E 0.18033688f /* 0.125 * log2(e), folded into Q at GEMM1 */
#define SLAB_STRIDE 8448           /* 64x64 bf16 O (8192) + 64 f32 rowsum (256) */

__device__ __forceinline__ f32x4 f32x4_zero() {
  f32x4 z = {0.f, 0.f, 0.f, 0.f};
  return z;
}

// async global->LDS DMA, 16B per lane. LDS dest = wave-uniform base + lane*16
// (linear); swizzled layouts realized by pre-swizzling the per-lane GLOBAL
// source address (rule #21). Drained by the vmcnt(0) before s_barrier.
__device__ __forceinline__ void async16(const __bf16* g, void* l) {
  __builtin_amdgcn_global_load_lds(
      (const __attribute__((address_space(1))) void*)g,
      (__attribute__((address_space(3))) void*)l, 16, 0, 0);
}

// ---------------- prep: f32 -> bf16 (vectorized) ----------------
__global__ __launch_bounds__(256) void cvt_f32_bf16(const float* __restrict__ in,
                                                    __bf16* __restrict__ out, int n8) {
  int i = blockIdx.x * 256 + threadIdx.x;
  if (i >= n8) return;
  f32x8 a = ((const f32x8*)in)[i];
  bf16x8 o;
#pragma unroll
  for (int j = 0; j < 8; ++j) o[j] = (__bf16)a[j];
  ((bf16x8*)out)[i] = o;
}

// ---------------- prep: transpose [768][N] f32 -> [N][768] bf16 ----------------
__global__ __launch_bounds__(256) void transpose_cvt(const float* __restrict__ in,
                                                     __bf16* __restrict__ out, int N) {
  __shared__ __bf16 t[64][72];  // padded
  int kb = blockIdx.x * 64, nb = blockIdx.y * 64;
  int c = threadIdx.x & 63, r0 = threadIdx.x >> 6;
#pragma unroll
  for (int i = 0; i < 16; ++i) {
    int r = r0 * 16 + i;
    t[c][r] = (__bf16)in[(size_t)(kb + r) * N + nb + c];
  }
  __syncthreads();
#pragma unroll
  for (int i = 0; i < 16; ++i) {
    int r = r0 * 16 + i;
    out[(size_t)(nb + r) * DMODEL + kb + c] = t[r][c];
  }
}

// ---------------- shared GEMM core: C[128x128] += A[128xK] * Bt[128xK]^T ----------------
__device__ __forceinline__ void gemm128_bt(const __bf16* __restrict__ A,
                                           const __bf16* __restrict__ Bt,
                                           int m0, int n0, int K,
                                           __bf16* Alds, __bf16* Blds,
                                           f32x4 acc[4][4]) {
  const int tid = threadIdx.x;
  const int l = tid & 63, w = tid >> 6;
  const int wr = w >> 1, wc = w & 1;
  const int g = l >> 4, ln = l & 15;

  const int rr = tid >> 3;
  const int sx = (tid & 7) ^ (rr & 7);
  const __bf16* As = A + (size_t)(m0 + rr) * K + sx * 8;
  const __bf16* Bs = Bt + (size_t)(n0 + rr) * K + sx * 8;
  char* Ad = (char*)Alds + (w << 10);
  char* Bd = (char*)Blds + (w << 10);

  for (int k0 = 0; k0 < K; k0 += 64) {
#pragma unroll
    for (int i = 0; i < 4; ++i) {
      async16(As + (size_t)(i * 32) * K + k0, Ad + i * 4096);
      async16(Bs + (size_t)(i * 32) * K + k0, Bd + i * 4096);
    }
    __syncthreads();
#pragma unroll
    for (int kk = 0; kk < 2; ++kk) {
      bf16x8 af[4], bfr[4];
#pragma unroll
      for (int mi = 0; mi < 4; ++mi) {
        int row = wr * 64 + mi * 16 + ln;
        af[mi] = *(const bf16x8*)(Alds + row * 64 + ((((kk << 2) + g) ^ (row & 7)) << 3));
      }
#pragma unroll
      for (int ni = 0; ni < 4; ++ni) {
        int row = wc * 64 + ni * 16 + ln;
        bfr[ni] = *(const bf16x8*)(Blds + row * 64 + ((((kk << 2) + g) ^ (row & 7)) << 3));
      }
#pragma unroll
      for (int mi = 0; mi < 4; ++mi)
#pragma unroll
        for (int ni = 0; ni < 4; ++ni)
          acc[mi][ni] =
              __builtin_amdgcn_mfma_f32_16x16x32_bf16(af[mi], bfr[ni], acc[mi][ni], 0, 0, 0);
    }
    __syncthreads();
  }
}

// ---------------- GEMM1: qkv = xb @ Wqkv + bqkv; Q pre-scaled by 0.125*log2e;
// scatter Q,K [B,H,S,Hd]; V transposed [B,H,Hd,S] ----------------
__global__ __launch_bounds__(256) void gemm_qkv(const __bf16* __restrict__ xb,
                                                const __bf16* __restrict__ Wt,
                                                const float* __restrict__ bqkv,
                                                __bf16* __restrict__ Qo,
                                                __bf16* __restrict__ Ko,
                                                __bf16* __restrict__ Vto) {
  __shared__ __bf16 Alds[128 * 64];
  __shared__ __bf16 Blds[128 * 64];
  int bm = blockIdx.x & 63, bn = blockIdx.x >> 6;
  int m0 = bm * 128, n0 = bn * 128;
  f32x4 acc[4][4];
#pragma unroll
  for (int i = 0; i < 4; ++i)
#pragma unroll
    for (int j = 0; j < 4; ++j) acc[i][j] = f32x4_zero();
  gemm128_bt(xb, Wt, m0, n0, DMODEL, Alds, Blds, acc);

  const int l = threadIdx.x & 63, w = threadIdx.x >> 6;
  const int wr = w >> 1, wc = w & 1, g = l >> 4, ln = l & 15;
#pragma unroll
  for (int ni = 0; ni < 4; ++ni) {
    int ncol = n0 + wc * 64 + ni * 16 + ln;
    int which = ncol / DMODEL;  // 0=q 1=k 2=v (uniform per 16-col fragment)
    int dd = ncol - which * DMODEL;
    int h = dd >> 6, hd = dd & 63;
    float bias = bqkv[ncol];
    if (which == 2) {
#pragma unroll
      for (int mi = 0; mi < 4; ++mi)
#pragma unroll
        for (int r = 0; r < 4; ++r) {
          int mrow = m0 + wr * 64 + mi * 16 + 4 * g + r;
          int b = mrow >> 12, s = mrow & (S_LEN - 1);
          float v = acc[mi][ni][r] + bias;
          Vto[(((size_t)(b * NH + h) * HD) + hd) * S_LEN + s] = (__bf16)v;
        }
    } else {
      __bf16* op = (which == 0) ? Qo : Ko;
      const float scl = (which == 0) ? SM_SCALE_LOG2E : 1.0f;
#pragma unroll
      for (int mi = 0; mi < 4; ++mi)
#pragma unroll
        for (int r = 0; r < 4; ++r) {
          int mrow = m0 + wr * 64 + mi * 16 + 4 * g + r;
          int b = mrow >> 12, s = mrow & (S_LEN - 1);
          float v = (acc[mi][ni][r] + bias) * scl;
          op[((((size_t)b * NH + h) * S_LEN) + s) * HD + hd] = (__bf16)v;
        }
    }
  }
}

// ---------------- GEMM2: out = Yb @ Wout + bout (fp32 out) ----------------
__global__ __launch_bounds__(256) void gemm_out(const __bf16* __restrict__ yb,
                                                const __bf16* __restrict__ Wt,
                                                const float* __restrict__ bout,
                                                float* __restrict__ out) {
  __shared__ __bf16 Alds[128 * 64];
  __shared__ __bf16 Blds[128 * 64];
  int bm = blockIdx.x & 63, bn = blockIdx.x >> 6;
  int m0 = bm * 128, n0 = bn * 128;
  f32x4 acc[4][4];
#pragma unroll
  for (int i = 0; i < 4; ++i)
#pragma unroll
    for (int j = 0; j < 4; ++j) acc[i][j] = f32x4_zero();
  gemm128_bt(yb, Wt, m0, n0, DMODEL, Alds, Blds, acc);

  const int l = threadIdx.x & 63, w = threadIdx.x >> 6;
  const int wr = w >> 1, wc = w & 1, g = l >> 4, ln = l & 15;
#pragma unroll
  for (int ni = 0; ni < 4; ++ni) {
    int ncol = n0 + wc * 64 + ni * 16 + ln;
    float bias = bout[ncol];
#pragma unroll
    for (int mi = 0; mi < 4; ++mi)
#pragma unroll
      for (int r = 0; r < 4; ++r) {
        int mrow = m0 + wr * 64 + mi * 16 + 4 * g + r;
        out[(size_t)mrow * DMODEL + ncol] = acc[mi][ni][r] + bias;
      }
  }
}

// ---------------- causal flash attention v15: v14 with KVBLK=32 ----------------
// Same decomposition (2304 units, kv-split chunks + combine) and same verified
// fragment machinery; KV tiles shrunk 64->32 kv: LDS = 2x(4K K + 4K V) dbuf +
// 4x1K P = 20KB -> 8 resident blocks/CU (= 160KB LDS, 100% wave ceiling; v14's
// 40KB allowed only 4). Iterations double, per-iter work halves; residency
// covers the barrier/DMA gaps. Masking evaluated per tile (wave-uniform).
__global__ __launch_bounds__(256) void attn_fwd15(const __bf16* __restrict__ Q,
                                                  const __bf16* __restrict__ K,
                                                  const __bf16* __restrict__ Vt,
                                                  __bf16* __restrict__ Y,
                                                  char* __restrict__ Po) {
  __shared__ __bf16 KVl[2][2][2048];  // [buf][K/V]; K: [32 kv][64 d], V: [64 d][32 kv]
  __shared__ char Plb[4][1024];       // per-wave P bounce [16 q][32 kv], pitch 64B + XOR

  const int tid = threadIdx.x;
  const int wv = tid >> 6, l = tid & 63;
  const int g = l >> 4, ln = l & 15;
  const int bi = blockIdx.x;
  const int xcd = bi & 7, j = bi >> 3;  // j in 0..287
  const int head = xcd * 3 + (j % 3);   // 3 heads per XCD
  const int r_ = j / 3;                 // rank 0..95, heavy-first

  int c, t0, t1, part;
  bool split;
  if (r_ < 64) {  // split chunks c=63..32, two kv halves each
    c = 63 - (r_ >> 1);
    part = r_ & 1;
    int T = c + 1;         // 64-kv tiles in chunk
    int h = (T + 1) >> 1;  // part0 size
    t0 = part ? h : 0;
    t1 = part ? T : h;
    split = true;
  } else {  // direct chunks c=31..0
    c = 95 - r_;
    part = 0;
    t0 = 0;
    t1 = c + 1;
    split = false;
  }
  const int it0 = 2 * t0, it1 = 2 * t1;  // 32-kv tile range
  const int q0 = 64 * c + 16 * wv;
  const int thr = 16 * wv + ln;  // chunk-local mask threshold at tile kv0=64c...

  const size_t hb = (size_t)head * (S_LEN * HD);
  const __bf16* Qh = Q + hb;
  const __bf16* Kh = K + hb;
  const __bf16* Vh = Vt + hb;  // [HD][S]

  const int swp = ln & 3;
  char* Pw = Plb[wv] + ln * 64;

  // staging lane geometry: K tile [32 kv][64 d] (8x16B granules/row),
  // V tile [64 d][32 kv] (4x16B granules/row); linear LDS dest, inverse-
  // swizzled global source.
  const int kr = tid >> 3;
  const int ks = (tid & 7) ^ (kr & 7);
  const size_t kL = (size_t)kr * HD + ks * 8;
  const int vr = tid >> 2;
  const int vs = (tid & 3) ^ (vr & 3);
  const size_t vL = (size_t)vr * S_LEN + vs * 8;
  const int ldsoff = wv << 10;  // wave's 1KB slice of each 4KB tile

  bf16x8 qf[2];
#pragma unroll
  for (int t = 0; t < 2; ++t)
    qf[t] = *(const bf16x8*)(Qh + (size_t)(q0 + ln) * HD + 32 * t + 8 * g);

  bf16x8 ones;
#pragma unroll
  for (int t = 0; t < 8; ++t) ones[t] = (__bf16)1.0f;

  f32x4 o[4], o5;
#pragma unroll
  for (int nt = 0; nt < 4; ++nt) o[nt] = f32x4_zero();
  o5 = f32x4_zero();

  // prologue: stage tile it0 into buf 0
  const __bf16* kq = Kh + (size_t)it0 * 32 * HD;
  const __bf16* vq = Vh + it0 * 32;
  {
    async16(kq + kL, (char*)&KVl[0][0][0] + ldsoff);
    async16(vq + vL, (char*)&KVl[0][1][0] + ldsoff);
    __syncthreads();
  }
  kq += (size_t)32 * HD;
  vq += 32;

  int cur = 0;
  for (int i = it0; i < it1; ++i) {
    const bool more = (i + 1) < it1;
    if (more) {  // DMA next tile into buf^1 (drained by end-of-iter barrier)
      async16(kq + kL, (char*)&KVl[cur ^ 1][0][0] + ldsoff);
      async16(vq + vL, (char*)&KVl[cur ^ 1][1][0] + ldsoff);
      kq += (size_t)32 * HD;
      vq += 32;
    }

    const __bf16* Kl = &KVl[cur][0][0];
    const __bf16* Vl = &KVl[cur][1][0];
    const int kv0 = 32 * i;
    const bool diag = (kv0 + 31) > q0;  // wave-uniform

    // ---- QK^T + fused softmax -> P bounce ----
    if (!diag) {
#pragma unroll
      for (int jt = 0; jt < 2; ++jt) {
        int row = 16 * jt + ln;
        bf16x8 kf0 = *(const bf16x8*)(Kl + row * 64 + ((g ^ (row & 7)) << 3));
        bf16x8 kf1 = *(const bf16x8*)(Kl + row * 64 + (((4 + g) ^ (row & 7)) << 3));
        f32x4 z = f32x4_zero();
        z = __builtin_amdgcn_mfma_f32_16x16x32_bf16(kf0, qf[0], z, 0, 0, 0);
        z = __builtin_amdgcn_mfma_f32_16x16x32_bf16(kf1, qf[1], z, 0, 0, 0);
        bf16x4 qd;
#pragma unroll
        for (int r = 0; r < 4; ++r) qd[r] = (__bf16)__builtin_exp2f(z[r]);
        *(bf16x4*)(Pw + ((((2 * jt + (g >> 1)) ^ swp) << 4) | ((g & 1) << 3))) = qd;
      }
    } else {
      const int thrL = q0 + ln - kv0;
#pragma unroll
      for (int jt = 0; jt < 2; ++jt) {
        int row = 16 * jt + ln;
        bf16x8 kf0 = *(const bf16x8*)(Kl + row * 64 + ((g ^ (row & 7)) << 3));
        bf16x8 kf1 = *(const bf16x8*)(Kl + row * 64 + (((4 + g) ^ (row & 7)) << 3));
        f32x4 z = f32x4_zero();
        z = __builtin_amdgcn_mfma_f32_16x16x32_bf16(kf0, qf[0], z, 0, 0, 0);
        z = __builtin_amdgcn_mfma_f32_16x16x32_bf16(kf1, qf[1], z, 0, 0, 0);
        bf16x4 qd;
#pragma unroll
        for (int r = 0; r < 4; ++r) {
          float pv = __builtin_exp2f(z[r]);
          if (16 * jt + 4 * g + r > thrL) pv = 0.f;
          qd[r] = (__bf16)pv;
        }
        *(bf16x4*)(Pw + ((((2 * jt + (g >> 1)) ^ swp) << 4) | ((g & 1) << 3))) = qd;
      }
    }

    // ---- PV + ones row-sum ----
    bf16x8 pa = *(const bf16x8*)(Pw + ((g ^ swp) << 4));
    __builtin_amdgcn_s_setprio(1);
    o5 = __builtin_amdgcn_mfma_f32_16x16x32_bf16(pa, ones, o5, 0, 0, 0);
#pragma unroll
    for (int nt = 0; nt < 4; ++nt) {
      int row = 16 * nt + ln;
      bf16x8 vf = *(const bf16x8*)(Vl + row * 32 + ((g ^ (row & 3)) << 3));
      o[nt] = __builtin_amdgcn_mfma_f32_16x16x32_bf16(pa, vf, o[nt], 0, 0, 0);
    }
    __builtin_amdgcn_s_setprio(0);

    if (more) __syncthreads();  // drains DMA (vmcnt0) + publishes buf^1
    cur ^= 1;
  }

  if (!split) {
    // direct write Y: lane holds O[q=4g+r][d=16nt+ln]
    const int bb = head / NH, hh = head - bb * NH;
    __bf16* Yp = Y + ((size_t)bb * S_LEN) * DMODEL + hh * HD;
#pragma unroll
    for (int r = 0; r < 4; ++r) {
      float inv = 1.0f / o5[r];
      int qr = q0 + 4 * g + r;
#pragma unroll
      for (int nt = 0; nt < 4; ++nt)
        Yp[(size_t)qr * DMODEL + 16 * nt + ln] = (__bf16)(o[nt][r] * inv);
    }
  } else {
    // partial slab: O bf16 [64 rows][64 d] + rowsum f32 [64]
    char* slab = Po + (size_t)(((head << 5) + (c - 32)) * 2 + part) * SLAB_STRIDE;
#pragma unroll
    for (int r = 0; r < 4; ++r) {
      int rowL = 16 * wv + 4 * g + r;
#pragma unroll
      for (int nt = 0; nt < 4; ++nt)
        *(__bf16*)(slab + (rowL * 64 + 16 * nt + ln) * 2) = (__bf16)o[nt][r];
      if (ln == 0) *(float*)(slab + 8192 + rowL * 4) = o5[r];
    }
  }
}

// ---------------- combine split-chunk partials (64-row chunks, 32 rows/block) ----------------
__global__ __launch_bounds__(256) void attn_combine(const char* __restrict__ Po,
                                                    __bf16* __restrict__ Y) {
  const int blk = blockIdx.x;  // 0..1535 = (head, chunk-32, half)
  const int head = blk >> 6, rem = blk & 63;
  const int cc = rem >> 1, half = rem & 1;
  const int c = cc + 32;
  const char* s0 = Po + (size_t)(((head << 5) + cc) * 2) * SLAB_STRIDE;
  const char* s1 = s0 + SLAB_STRIDE;
  const int tid = threadIdx.x;
  const int row = half * 32 + (tid >> 3), d0 = (tid & 7) * 8;

  bf16x8 a = *(const bf16x8*)(s0 + (row * 64 + d0) * 2);
  bf16x8 b = *(const bf16x8*)(s1 + (row * 64 + d0) * 2);
  float rs = *(const float*)(s0 + 8192 + row * 4) + *(const float*)(s1 + 8192 + row * 4);
  float inv = 1.0f / rs;

  const int bb = head / NH, hh = head - bb * NH;
  __bf16* yp = Y + ((size_t)bb * S_LEN + 64 * c + row) * DMODEL + hh * HD + d0;
  bf16x8 o;
#pragma unroll
  for (int j = 0; j < 8; ++j) o[j] = (__bf16)(((float)a[j] + (float)b[j]) * inv);
  *(bf16x8*)yp = o;
}

extern "C" void kernel_launch(void* const* d_in, const int* in_sizes, int n_in,
                              void* d_out, int out_size, void* d_ws, size_t ws_size,
                              hipStream_t stream) {
  const float* x = (const float*)d_in[0];
  const float* Wqkv = (const float*)d_in[1];
  const float* bqkv = (const float*)d_in[2];
  const float* Wout = (const float*)d_in[3];
  const float* bout = (const float*)d_in[4];
  float* out = (float*)d_out;

  char* ws = (char*)d_ws;
  size_t off = 0;
  auto take = [&](size_t bytes) {
    char* p = ws + off;
    off += bytes;
    return p;
  };
  const size_t MD2 = (size_t)MTOT * DMODEL * 2;
  __bf16* xb = (__bf16*)take(MD2);
  __bf16* Wqkv_t = (__bf16*)take((size_t)3 * DMODEL * DMODEL * 2);
  __bf16* Wout_t = (__bf16*)take((size_t)DMODEL * DMODEL * 2);
  __bf16* Qb = (__bf16*)take(MD2);
  __bf16* Kb = (__bf16*)take(MD2);
  __bf16* Vtb = (__bf16*)take(MD2);
  __bf16* Yb = (__bf16*)take(MD2);
  char* Po = take((size_t)1536 * SLAB_STRIDE);  // 24 heads x 32 split chunks x 2 parts

  int n8 = MTOT * DMODEL / 8;
  cvt_f32_bf16<<<(n8 + 255) / 256, 256, 0, stream>>>(x, xb, n8);
  transpose_cvt<<<dim3(DMODEL / 64, 3 * DMODEL / 64), 256, 0, stream>>>(Wqkv, Wqkv_t, 3 * DMODEL);
  transpose_cvt<<<dim3(DMODEL / 64, DMODEL / 64), 256, 0, stream>>>(Wout, Wout_t, DMODEL);
  gemm_qkv<<<64 * (3 * DMODEL / 128), 256, 0, stream>>>(xb, Wqkv_t, bqkv, Qb, Kb, Vtb);
  attn_fwd15<<<2304, 256, 0, stream>>>(Qb, Kb, Vtb, Yb, Po);
  attn_combine<<<1536, 256, 0, stream>>>(Po, Yb);
  gemm_out<<<64 * (DMODEL / 128), 256, 0, stream>>>(Yb, Wout_t, bout, out);
}